// Round 7
// baseline (260.419 us; speedup 1.0000x reference)
//
#include <hip/hip_runtime.h>
#include <hip/hip_bf16.h>

#define N_PTS 16384
#define PER   2048
#define M_CTR 4096
#define KNB   64
#define C_IN  128
#define HID   256
#define C_OUT 256

typedef unsigned short u16;
typedef unsigned int u32;
typedef __attribute__((ext_vector_type(8))) short s8v;    // 8 bf16 (4 VGPRs)
typedef __attribute__((ext_vector_type(4))) float f4v;
typedef __attribute__((ext_vector_type(4))) unsigned int u4v;

static __device__ __forceinline__ u16 f2bf(float f) {
    union { float f; unsigned int i; } v; v.f = f;
    unsigned int r = v.i + 0x7FFFu + ((v.i >> 16) & 1u);
    return (u16)(r >> 16);
}

// ---------------------------------------------------------------- fused ballq (blocks 0..4095) + gemm_xw (blocks 4096..4415)
// The two halves are data-independent (ballq: pos -> nbr/cnt; gemm: x,W1 -> u,v),
// so they co-run in one dispatch. W2T prep (consumed by edge, NEXT dispatch)
// is folded into ballq blocks 0..255. gemm reads W1 directly (scalar f32 ->
// bf16 pack) so no W1aT/W1bT prep dependency exists.
__global__ __launch_bounds__(256) void work_kernel(
        const float* __restrict__ pos, int* __restrict__ nbr, int* __restrict__ cnt,
        const float* __restrict__ W1, const float* __restrict__ W2,
        u16* __restrict__ W2T,
        const float* __restrict__ x, const float* __restrict__ b1,
        u16* __restrict__ u_out, float* __restrict__ v_out) {
    __shared__ char arena[64 * 136 * 2];                  // 17408 B, unioned
    int blk = blockIdx.x, tid = threadIdx.x;

    if (blk < M_CTR) {
        // ================= ballq =================
        float* cd2 = (float*)arena;                       // [1024]
        int*   cidx = (int*)(arena + 4096);               // [1024]
        __shared__ int s_n;
        int m = blk;

        if (m < 256) {                                    // W2T prep for edge
            int gid = m * 256 + tid;
            int cc = gid >> 8, k = gid & 255;
            W2T[gid] = f2bf(W2[k * 256 + cc]);            // W2T[c][k]
        }

        int c = m * 4;
        int base = (m >> 9) << 11;                        // cloud start
        int ln = tid & 63;
        if (tid == 0) s_n = 0;
        __syncthreads();
        float cx = pos[c * 3 + 0], cy = pos[c * 3 + 1], cz = pos[c * 3 + 2];
        float A = __fadd_rn(__fadd_rn(__fmul_rn(cx, cx), __fmul_rn(cy, cy)), __fmul_rn(cz, cz));
        float c2x = __fmul_rn(2.0f, cx);
        float c2y = __fmul_rn(2.0f, cy);
        float c2z = __fmul_rn(2.0f, cz);
        for (int s = 0; s < 8; ++s) {
            int j = base + tid + (s << 8);
            float px = pos[j * 3 + 0], py = pos[j * 3 + 1], pz = pos[j * 3 + 2];
            float B = __fadd_rn(__fadd_rn(__fmul_rn(px, px), __fmul_rn(py, py)), __fmul_rn(pz, pz));
            float C = __fmaf_rn(c2z, pz, __fmaf_rn(c2y, py, __fmul_rn(c2x, px)));
            float d2 = __fsub_rn(__fadd_rn(A, B), C);
            bool hit = (d2 <= 0.0625f);
            unsigned long long mk = __ballot(hit);
            int nb = __popcll(mk & ((1ull << ln) - 1ull));
            int tot = __popcll(mk);
            int bidx = 0;
            if (ln == 0 && tot) bidx = atomicAdd(&s_n, tot);
            bidx = __shfl(bidx, 0, 64);
            if (hit) {
                int a = bidx + nb;
                if (a < 1024) { cd2[a] = d2; cidx[a] = j; }
            }
        }
        __syncthreads();
        int V = s_n < 1024 ? s_n : 1024;
        if (V <= KNB) {
            if (tid < KNB) nbr[m * KNB + tid] = (tid < V) ? cidx[tid] : c;
            if (tid == 0) cnt[m] = V;
        } else {
            for (int e = tid; e < V; e += 256) {
                float de = cd2[e]; int ie = cidx[e];
                int rank = 0;
                for (int q = 0; q < V; ++q) {
                    float dq = cd2[q];
                    rank += (dq < de) || (dq == de && cidx[q] < ie);
                }
                if (rank < KNB) nbr[m * KNB + rank] = cidx[e];
            }
            if (tid == 0) cnt[m] = KNB;
        }
    } else {
        // ================= gemm_xw =================
        u16* x_lds = (u16*)arena;                         // [64*136]
        int blk2 = blk - M_CTR;
        int mode = blk2 >= 256 ? 1 : 0;
        int bb = mode ? blk2 - 256 : blk2;
        const float* W1x = W1 + (mode ? 128 * 256 : 0);   // W1 rows [128*mode ..)
        {
            int r = tid >> 2, q = tid & 3;
            int xrow = bb * 64 + r;
            if (mode) xrow *= 4;
            const float* xp = x + xrow * C_IN + q * 32;
            u16* dst = x_lds + r * 136 + q * 32;
            for (int i = 0; i < 8; ++i) {
                f4v f = *(const f4v*)(xp + i * 4);
                dst[i * 4 + 0] = f2bf(f[0]);
                dst[i * 4 + 1] = f2bf(f[1]);
                dst[i * 4 + 2] = f2bf(f[2]);
                dst[i * 4 + 3] = f2bf(f[3]);
            }
        }
        __syncthreads();
        int lane = tid & 63, w = tid >> 6;
        int quad = lane >> 4, l16 = lane & 15;
        int cb = w * 64;
        f4v acc[4][4] = {};
        for (int k0 = 0; k0 < 128; k0 += 32) {
            s8v a[4], b[4];
            #pragma unroll
            for (int ct = 0; ct < 4; ++ct) {
                int col = cb + ct * 16 + l16;
                const float* wp = W1x + (k0 + quad * 8) * 256 + col;
                union { u4v v4; s8v s8; } pk;
                #pragma unroll
                for (int d = 0; d < 4; ++d) {
                    u16 lo = f2bf(wp[(2 * d) * 256]);
                    u16 hi = f2bf(wp[(2 * d + 1) * 256]);
                    pk.v4[d] = ((u32)hi << 16) | lo;
                }
                b[ct] = pk.s8;
            }
            #pragma unroll
            for (int rt = 0; rt < 4; ++rt)
                a[rt] = *(const s8v*)&x_lds[(rt * 16 + l16) * 136 + k0 + quad * 8];
            #pragma unroll
            for (int rt = 0; rt < 4; ++rt)
                #pragma unroll
                for (int ct = 0; ct < 4; ++ct)
                    acc[rt][ct] = __builtin_amdgcn_mfma_f32_16x16x32_bf16(a[rt], b[ct], acc[rt][ct], 0, 0, 0);
        }
        for (int rt = 0; rt < 4; ++rt)
            for (int ct = 0; ct < 4; ++ct)
                for (int g = 0; g < 4; ++g) {
                    int row = rt * 16 + quad * 4 + g;
                    int col = cb + ct * 16 + l16;
                    float val = acc[rt][ct][g];
                    int orow = bb * 64 + row;
                    if (mode == 0) u_out[orow * 256 + col] = f2bf(val);
                    else           v_out[orow * 256 + col] = val + b1[col];
                }
    }
}

// ---------------------------------------------------------------- fused edge conv
// 512 threads = 8 waves; M-tile 128 (2 centers); 4 pairs/block; grid 512.
// SINGLE h buffer (79.3 KB total LDS) -> 2 blocks/CU -> 4 waves/SIMD: cross-
// block wave overlap hides u-gather latency and barrier drains (r6 lesson:
// 2 waves/SIMD left ~55 us of stalls). Two barriers per pair. Meta (nbr/relc/
// v/cnt) stays double-buffered + prefetched. (512,4): 128-VGPR cap, measured
// fit in r5/r6.
__global__ __launch_bounds__(512, 4) void edge_kernel(
        const u16* __restrict__ u, const float* __restrict__ v,
        const u16* __restrict__ W2T, const float* __restrict__ W1,
        const float* __restrict__ b2, const float* __restrict__ pos,
        const float* __restrict__ lframes, const int* __restrict__ batch,
        const int* __restrict__ nbrg, const int* __restrict__ cnt,
        float* __restrict__ out0, float* __restrict__ out_pos,
        float* __restrict__ out_batch, float* __restrict__ out_lf) {
    __shared__ u16   h_lds[128 * 264];                   // 67584 B
    __shared__ float v_lds[2][2][256];                   // 4096 B
    __shared__ float w1c_lds[768];                       // 3072 B
    __shared__ f4v   relc_lds[2][2][64];                 // 4096 B
    __shared__ u16   nbr_lds[2][2][64];                  // 512 B

    int blk = blockIdx.x, tid = threadIdx.x;
    int m0 = ((blk & 7) << 9) | ((blk >> 3) << 3);       // 8 consecutive centers, cloud == XCD

    int lane = tid & 63, w = tid >> 6;
    int quad = lane >> 4, l16 = lane & 15;
    int cb = (w & 3) * 64;
    int rbase = (w >> 2) * 64;
    int gsel = w >> 2;

    // ---- prologue
    for (int i = tid; i < 768; i += 512) w1c_lds[i] = W1[65536 + i];
    if (tid < 128) {                                     // meta for pair 0
        int g = tid >> 6, t = tid & 63;
        int mm = m0 + g, cc = mm * 4;
        int j = nbrg[mm * KNB + t];
        nbr_lds[0][g][t] = (u16)j;
        float rx = pos[j * 3 + 0] - pos[cc * 3 + 0];
        float ry = pos[j * 3 + 1] - pos[cc * 3 + 1];
        float rz = pos[j * 3 + 2] - pos[cc * 3 + 2];
        const float* lf = lframes + cc * 9;
        f4v r;
        r[0] = lf[0] * rx + lf[1] * ry + lf[2] * rz;
        r[1] = lf[3] * rx + lf[4] * ry + lf[5] * rz;
        r[2] = lf[6] * rx + lf[7] * ry + lf[8] * rz;
        r[3] = 0.0f;
        relc_lds[0][g][t] = r;
    }
    v_lds[0][tid >> 8][tid & 255] = v[(m0 + (tid >> 8)) * 256 + (tid & 255)];
    if (tid >= 256 && tid < 384) {                       // aux outputs, all 8 centers
        int g = (tid - 256) >> 4, t = tid & 15;
        int mm = m0 + g, cc = mm * 4;
        if (t < 3)            out_pos[mm * 3 + t] = pos[cc * 3 + t];
        else if (t == 3)      out_batch[mm] = (float)batch[cc];
        else if (t < 13)      out_lf[mm * 9 + (t - 4)] = lframes[cc * 9 + (t - 4)];
    }

    int co = (tid & 31) * 8;
    int rs = tid >> 5;                                   // 0..15
    int cv_cur = cnt[m0 + gsel];
    __syncthreads();                                     // meta[0] + w1c ready

    int cv_next = 0;
    for (int p = 0; p < 4; ++p) {
        int pb = p & 1;
        // ---- phase 1: h[128][256] = relu(u[nbr] + v + relc @ W1c)
        #pragma unroll
        for (int g = 0; g < 2; ++g) {
            f4v vq0 = *(const f4v*)&v_lds[pb][g][co];
            f4v vq1 = *(const f4v*)&v_lds[pb][g][co + 4];
            f4v wa0 = *(const f4v*)&w1c_lds[co],       wa1 = *(const f4v*)&w1c_lds[co + 4];
            f4v wb0 = *(const f4v*)&w1c_lds[256 + co], wb1 = *(const f4v*)&w1c_lds[256 + co + 4];
            f4v wc0 = *(const f4v*)&w1c_lds[512 + co], wc1 = *(const f4v*)&w1c_lds[512 + co + 4];
            #pragma unroll
            for (int i2 = 0; i2 < 4; ++i2) {
                int rl = rs + i2 * 16;
                int row = g * 64 + rl;
                int j = (int)nbr_lds[pb][g][rl];
                u4v uu = *(const u4v*)(u + j * 256 + co);
                f4v r = relc_lds[pb][g][rl];
                float p8[8];
                #pragma unroll
                for (int e = 0; e < 8; ++e) {
                    u32 bits = (e & 1) ? (uu[e >> 1] & 0xFFFF0000u) : (uu[e >> 1] << 16);
                    float va = (e < 4) ? vq0[e] : vq1[e - 4];
                    float a0 = (e < 4) ? wa0[e] : wa1[e - 4];
                    float b0 = (e < 4) ? wb0[e] : wb1[e - 4];
                    float c0 = (e < 4) ? wc0[e] : wc1[e - 4];
                    float pre = fmaf(r[0], a0, fmaf(r[1], b0, fmaf(r[2], c0,
                                  va + __uint_as_float(bits))));
                    p8[e] = fmaxf(pre, 0.0f);
                }
                u4v pk;
                #pragma unroll
                for (int d = 0; d < 4; ++d)
                    pk[d] = __builtin_amdgcn_perm(__float_as_uint(p8[2 * d + 1]),
                                                  __float_as_uint(p8[2 * d]), 0x07060302u);
                *(u4v*)&h_lds[row * 264 + co] = pk;
            }
        }
        // ---- prefetch next pair's metadata into the other buffer
        if (p < 3) {
            int nb = pb ^ 1;
            int mbase = m0 + (p + 1) * 2;
            cv_next = cnt[mbase + gsel];
            if (tid < 128) {
                int g = tid >> 6, t = tid & 63;
                int mm = mbase + g, cc = mm * 4;
                int j = nbrg[mm * KNB + t];
                nbr_lds[nb][g][t] = (u16)j;
                float rx = pos[j * 3 + 0] - pos[cc * 3 + 0];
                float ry = pos[j * 3 + 1] - pos[cc * 3 + 1];
                float rz = pos[j * 3 + 2] - pos[cc * 3 + 2];
                const float* lf = lframes + cc * 9;
                f4v r;
                r[0] = lf[0] * rx + lf[1] * ry + lf[2] * rz;
                r[1] = lf[3] * rx + lf[4] * ry + lf[5] * rz;
                r[2] = lf[6] * rx + lf[7] * ry + lf[8] * rz;
                r[3] = 0.0f;
                relc_lds[nb][g][t] = r;
            }
            v_lds[nb][tid >> 8][tid & 255] = v[(mbase + (tid >> 8)) * 256 + (tid & 255)];
        }
        __syncthreads();                                 // h ready (+ meta[nb])

        // ---- phase 2: [128x256] @ [256x256], B streamed from L2/L1
        f4v acc[4][4] = {};
        for (int k0 = 0; k0 < 256; k0 += 32) {
            s8v a[4], b[4];
            #pragma unroll
            for (int rt = 0; rt < 4; ++rt)
                a[rt] = *(const s8v*)&h_lds[(rbase + rt * 16 + l16) * 264 + k0 + quad * 8];
            #pragma unroll
            for (int ct = 0; ct < 4; ++ct)
                b[ct] = *(const s8v*)(W2T + (cb + ct * 16 + l16) * 256 + k0 + quad * 8);
            #pragma unroll
            for (int rt = 0; rt < 4; ++rt)
                #pragma unroll
                for (int ct = 0; ct < 4; ++ct)
                    acc[rt][ct] = __builtin_amdgcn_mfma_f32_16x16x32_bf16(a[rt], b[ct], acc[rt][ct], 0, 0, 0);
        }
        // ---- epilogue: masked max over this wave's center, + b2
        int mout = m0 + p * 2 + gsel;
        #pragma unroll
        for (int ct = 0; ct < 4; ++ct) {
            float mx = -__builtin_inff();
            #pragma unroll
            for (int rt = 0; rt < 4; ++rt)
                #pragma unroll
                for (int g = 0; g < 4; ++g) {
                    int row = rt * 16 + quad * 4 + g;
                    float val = acc[rt][ct][g];
                    if (row < cv_cur) mx = fmaxf(mx, val);
                }
            mx = fmaxf(mx, __shfl_xor(mx, 16, 64));
            mx = fmaxf(mx, __shfl_xor(mx, 32, 64));
            if (lane < 16)
                out0[mout * 256 + cb + ct * 16 + l16] = mx + b2[cb + ct * 16 + l16];
        }
        cv_cur = cv_next;
        __syncthreads();                                 // h consumed before next overwrite
    }
}

extern "C" void kernel_launch(void* const* d_in, const int* in_sizes, int n_in,
                              void* d_out, int out_size, void* d_ws, size_t ws_size,
                              hipStream_t stream) {
    const float* x       = (const float*)d_in[0];
    const float* pos     = (const float*)d_in[1];
    const int*   batch   = (const int*)d_in[2];
    const float* lframes = (const float*)d_in[3];
    const float* W1      = (const float*)d_in[4];
    const float* b1      = (const float*)d_in[5];
    const float* W2      = (const float*)d_in[6];
    const float* b2      = (const float*)d_in[7];

    float* out       = (float*)d_out;
    float* out_pos   = out + M_CTR * 256;
    float* out_batch = out_pos + M_CTR * 3;
    float* out_lf    = out_batch + M_CTR;

    char* ws = (char*)d_ws;
    u16*   u_ws = (u16*)(ws);                    // N*256 bf16   = 8 MB
    float* v_ws = (float*)(ws + 8388608);        // M*256 f32    = 4 MB
    u16*   W2T  = (u16*)(ws + 12713984);         // 256*256 bf16
    int*   nbr  = (int*)(ws + 12845056);         // M*64 int
    int*   cntp = (int*)(ws + 13893632);         // M int

    hipLaunchKernelGGL(work_kernel, dim3(M_CTR + 320), dim3(256), 0, stream,
                       pos, nbr, cntp, W1, W2, W2T, x, b1, u_ws, v_ws);
    hipLaunchKernelGGL(edge_kernel, dim3(512), dim3(512), 0, stream,
                       u_ws, v_ws, W2T, W1, b2, pos, lframes, batch, nbr, cntp,
                       out, out_pos, out_batch, out_lf);
}

// Round 8
// 202.466 us; speedup vs baseline: 1.2862x; 1.2862x over previous
//
#include <hip/hip_runtime.h>
#include <hip/hip_bf16.h>

#define N_PTS 16384
#define PER   2048
#define M_CTR 4096
#define KNB   64
#define C_IN  128
#define HID   256
#define C_OUT 256

typedef unsigned short u16;
typedef unsigned int u32;
typedef __attribute__((ext_vector_type(8))) short s8v;    // 8 bf16 (4 VGPRs)
typedef __attribute__((ext_vector_type(4))) float f4v;
typedef __attribute__((ext_vector_type(4))) unsigned int u4v;

static __device__ __forceinline__ u16 f2bf(float f) {
    union { float f; unsigned int i; } v; v.f = f;
    unsigned int r = v.i + 0x7FFFu + ((v.i >> 16) & 1u);
    return (u16)(r >> 16);
}

// ---------------------------------------------------------------- fused ballq (blocks 0..4095) + gemm_xw (blocks 4096..4415)
// Data-independent halves co-run in one dispatch. W2T prep (consumed next
// dispatch) folded into ballq blocks 0..255. gemm reads W1 directly.
__global__ __launch_bounds__(256) void work_kernel(
        const float* __restrict__ pos, int* __restrict__ nbr, int* __restrict__ cnt,
        const float* __restrict__ W1, const float* __restrict__ W2,
        u16* __restrict__ W2T,
        const float* __restrict__ x, const float* __restrict__ b1,
        u16* __restrict__ u_out, float* __restrict__ v_out) {
    __shared__ char arena[64 * 136 * 2];                  // 17408 B, unioned
    int blk = blockIdx.x, tid = threadIdx.x;

    if (blk < M_CTR) {
        // ================= ballq =================
        float* cd2 = (float*)arena;                       // [1024]
        int*   cidx = (int*)(arena + 4096);               // [1024]
        __shared__ int s_n;
        int m = blk;

        if (m < 256) {                                    // W2T prep for edge
            int gid = m * 256 + tid;
            int cc = gid >> 8, k = gid & 255;
            W2T[gid] = f2bf(W2[k * 256 + cc]);            // W2T[c][k]
        }

        int c = m * 4;
        int base = (m >> 9) << 11;                        // cloud start
        int ln = tid & 63;
        if (tid == 0) s_n = 0;
        __syncthreads();
        float cx = pos[c * 3 + 0], cy = pos[c * 3 + 1], cz = pos[c * 3 + 2];
        float A = __fadd_rn(__fadd_rn(__fmul_rn(cx, cx), __fmul_rn(cy, cy)), __fmul_rn(cz, cz));
        float c2x = __fmul_rn(2.0f, cx);
        float c2y = __fmul_rn(2.0f, cy);
        float c2z = __fmul_rn(2.0f, cz);
        for (int s = 0; s < 8; ++s) {
            int j = base + tid + (s << 8);
            float px = pos[j * 3 + 0], py = pos[j * 3 + 1], pz = pos[j * 3 + 2];
            float B = __fadd_rn(__fadd_rn(__fmul_rn(px, px), __fmul_rn(py, py)), __fmul_rn(pz, pz));
            float C = __fmaf_rn(c2z, pz, __fmaf_rn(c2y, py, __fmul_rn(c2x, px)));
            float d2 = __fsub_rn(__fadd_rn(A, B), C);
            bool hit = (d2 <= 0.0625f);
            unsigned long long mk = __ballot(hit);
            int nb = __popcll(mk & ((1ull << ln) - 1ull));
            int tot = __popcll(mk);
            int bidx = 0;
            if (ln == 0 && tot) bidx = atomicAdd(&s_n, tot);
            bidx = __shfl(bidx, 0, 64);
            if (hit) {
                int a = bidx + nb;
                if (a < 1024) { cd2[a] = d2; cidx[a] = j; }
            }
        }
        __syncthreads();
        int V = s_n < 1024 ? s_n : 1024;
        if (V <= KNB) {
            if (tid < KNB) nbr[m * KNB + tid] = (tid < V) ? cidx[tid] : c;
            if (tid == 0) cnt[m] = V;
        } else {
            for (int e = tid; e < V; e += 256) {
                float de = cd2[e]; int ie = cidx[e];
                int rank = 0;
                for (int q = 0; q < V; ++q) {
                    float dq = cd2[q];
                    rank += (dq < de) || (dq == de && cidx[q] < ie);
                }
                if (rank < KNB) nbr[m * KNB + rank] = cidx[e];
            }
            if (tid == 0) cnt[m] = KNB;
        }
    } else {
        // ================= gemm_xw =================
        u16* x_lds = (u16*)arena;                         // [64*136]
        int blk2 = blk - M_CTR;
        int mode = blk2 >= 256 ? 1 : 0;
        int bb = mode ? blk2 - 256 : blk2;
        const float* W1x = W1 + (mode ? 128 * 256 : 0);
        {
            int r = tid >> 2, q = tid & 3;
            int xrow = bb * 64 + r;
            if (mode) xrow *= 4;
            const float* xp = x + xrow * C_IN + q * 32;
            u16* dst = x_lds + r * 136 + q * 32;
            for (int i = 0; i < 8; ++i) {
                f4v f = *(const f4v*)(xp + i * 4);
                dst[i * 4 + 0] = f2bf(f[0]);
                dst[i * 4 + 1] = f2bf(f[1]);
                dst[i * 4 + 2] = f2bf(f[2]);
                dst[i * 4 + 3] = f2bf(f[3]);
            }
        }
        __syncthreads();
        int lane = tid & 63, w = tid >> 6;
        int quad = lane >> 4, l16 = lane & 15;
        int cb = w * 64;
        f4v acc[4][4] = {};
        for (int k0 = 0; k0 < 128; k0 += 32) {
            s8v a[4], b[4];
            #pragma unroll
            for (int ct = 0; ct < 4; ++ct) {
                int col = cb + ct * 16 + l16;
                const float* wp = W1x + (k0 + quad * 8) * 256 + col;
                union { u4v v4; s8v s8; } pk;
                #pragma unroll
                for (int d = 0; d < 4; ++d) {
                    u16 lo = f2bf(wp[(2 * d) * 256]);
                    u16 hi = f2bf(wp[(2 * d + 1) * 256]);
                    pk.v4[d] = ((u32)hi << 16) | lo;
                }
                b[ct] = pk.s8;
            }
            #pragma unroll
            for (int rt = 0; rt < 4; ++rt)
                a[rt] = *(const s8v*)&x_lds[(rt * 16 + l16) * 136 + k0 + quad * 8];
            #pragma unroll
            for (int rt = 0; rt < 4; ++rt)
                #pragma unroll
                for (int ct = 0; ct < 4; ++ct)
                    acc[rt][ct] = __builtin_amdgcn_mfma_f32_16x16x32_bf16(a[rt], b[ct], acc[rt][ct], 0, 0, 0);
        }
        for (int rt = 0; rt < 4; ++rt)
            for (int ct = 0; ct < 4; ++ct)
                for (int g = 0; g < 4; ++g) {
                    int row = rt * 16 + quad * 4 + g;
                    int col = cb + ct * 16 + l16;
                    float val = acc[rt][ct][g];
                    int orow = bb * 64 + row;
                    if (mode == 0) u_out[orow * 256 + col] = f2bf(val);
                    else           v_out[orow * 256 + col] = val + b1[col];
                }
    }
}

// ---------------------------------------------------------------- fused edge conv
// 512 threads = 8 waves; M-tile 128; 4 pairs/block; grid 512. Single h buffer:
// 79 KB LDS -> 2 blocks/CU -> 4 waves/SIMD (occupancy via LDS, NOT via
// launch_bounds). (512,2) = 128-VGPR cap: the ONLY no-spill config measured
// (r4/r7: arg2=4 caps at 64 VGPR -> 300 MB scratch traffic; r5/r6: arg2=2 ->
// 128 VGPR, zero spill). Cross-block MFMA/VALU overlap hides barrier drains.
__global__ __launch_bounds__(512, 2) void edge_kernel(
        const u16* __restrict__ u, const float* __restrict__ v,
        const u16* __restrict__ W2T, const float* __restrict__ W1,
        const float* __restrict__ b2, const float* __restrict__ pos,
        const float* __restrict__ lframes, const int* __restrict__ batch,
        const int* __restrict__ nbrg, const int* __restrict__ cnt,
        float* __restrict__ out0, float* __restrict__ out_pos,
        float* __restrict__ out_batch, float* __restrict__ out_lf) {
    __shared__ u16   h_lds[128 * 264];                   // 67584 B
    __shared__ float v_lds[2][2][256];                   // 4096 B
    __shared__ float w1c_lds[768];                       // 3072 B
    __shared__ f4v   relc_lds[2][2][64];                 // 4096 B
    __shared__ u16   nbr_lds[2][2][64];                  // 512 B

    int blk = blockIdx.x, tid = threadIdx.x;
    int m0 = ((blk & 7) << 9) | ((blk >> 3) << 3);       // 8 consecutive centers, cloud == XCD

    int lane = tid & 63, w = tid >> 6;
    int quad = lane >> 4, l16 = lane & 15;
    int cb = (w & 3) * 64;
    int rbase = (w >> 2) * 64;
    int gsel = w >> 2;

    // ---- prologue
    for (int i = tid; i < 768; i += 512) w1c_lds[i] = W1[65536 + i];
    if (tid < 128) {                                     // meta for pair 0
        int g = tid >> 6, t = tid & 63;
        int mm = m0 + g, cc = mm * 4;
        int j = nbrg[mm * KNB + t];
        nbr_lds[0][g][t] = (u16)j;
        float rx = pos[j * 3 + 0] - pos[cc * 3 + 0];
        float ry = pos[j * 3 + 1] - pos[cc * 3 + 1];
        float rz = pos[j * 3 + 2] - pos[cc * 3 + 2];
        const float* lf = lframes + cc * 9;
        f4v r;
        r[0] = lf[0] * rx + lf[1] * ry + lf[2] * rz;
        r[1] = lf[3] * rx + lf[4] * ry + lf[5] * rz;
        r[2] = lf[6] * rx + lf[7] * ry + lf[8] * rz;
        r[3] = 0.0f;
        relc_lds[0][g][t] = r;
    }
    v_lds[0][tid >> 8][tid & 255] = v[(m0 + (tid >> 8)) * 256 + (tid & 255)];
    if (tid >= 256 && tid < 384) {                       // aux outputs, all 8 centers
        int g = (tid - 256) >> 4, t = tid & 15;
        int mm = m0 + g, cc = mm * 4;
        if (t < 3)            out_pos[mm * 3 + t] = pos[cc * 3 + t];
        else if (t == 3)      out_batch[mm] = (float)batch[cc];
        else if (t < 13)      out_lf[mm * 9 + (t - 4)] = lframes[cc * 9 + (t - 4)];
    }

    int co = (tid & 31) * 8;
    int rs = tid >> 5;                                   // 0..15
    int cv_cur = cnt[m0 + gsel];
    __syncthreads();                                     // meta[0] + w1c ready

    int cv_next = 0;
    for (int p = 0; p < 4; ++p) {
        int pb = p & 1;
        // ---- phase 1: h[128][256] = relu(u[nbr] + v + relc @ W1c)
        #pragma unroll
        for (int g = 0; g < 2; ++g) {
            f4v vq0 = *(const f4v*)&v_lds[pb][g][co];
            f4v vq1 = *(const f4v*)&v_lds[pb][g][co + 4];
            f4v wa0 = *(const f4v*)&w1c_lds[co],       wa1 = *(const f4v*)&w1c_lds[co + 4];
            f4v wb0 = *(const f4v*)&w1c_lds[256 + co], wb1 = *(const f4v*)&w1c_lds[256 + co + 4];
            f4v wc0 = *(const f4v*)&w1c_lds[512 + co], wc1 = *(const f4v*)&w1c_lds[512 + co + 4];
            #pragma unroll
            for (int i2 = 0; i2 < 4; ++i2) {
                int rl = rs + i2 * 16;
                int row = g * 64 + rl;
                int j = (int)nbr_lds[pb][g][rl];
                u4v uu = *(const u4v*)(u + j * 256 + co);
                f4v r = relc_lds[pb][g][rl];
                float p8[8];
                #pragma unroll
                for (int e = 0; e < 8; ++e) {
                    u32 bits = (e & 1) ? (uu[e >> 1] & 0xFFFF0000u) : (uu[e >> 1] << 16);
                    float va = (e < 4) ? vq0[e] : vq1[e - 4];
                    float a0 = (e < 4) ? wa0[e] : wa1[e - 4];
                    float b0 = (e < 4) ? wb0[e] : wb1[e - 4];
                    float c0 = (e < 4) ? wc0[e] : wc1[e - 4];
                    float pre = fmaf(r[0], a0, fmaf(r[1], b0, fmaf(r[2], c0,
                                  va + __uint_as_float(bits))));
                    p8[e] = fmaxf(pre, 0.0f);
                }
                u4v pk;
                #pragma unroll
                for (int d = 0; d < 4; ++d)
                    pk[d] = __builtin_amdgcn_perm(__float_as_uint(p8[2 * d + 1]),
                                                  __float_as_uint(p8[2 * d]), 0x07060302u);
                *(u4v*)&h_lds[row * 264 + co] = pk;
            }
        }
        // ---- prefetch next pair's metadata into the other buffer
        if (p < 3) {
            int nb = pb ^ 1;
            int mbase = m0 + (p + 1) * 2;
            cv_next = cnt[mbase + gsel];
            if (tid < 128) {
                int g = tid >> 6, t = tid & 63;
                int mm = mbase + g, cc = mm * 4;
                int j = nbrg[mm * KNB + t];
                nbr_lds[nb][g][t] = (u16)j;
                float rx = pos[j * 3 + 0] - pos[cc * 3 + 0];
                float ry = pos[j * 3 + 1] - pos[cc * 3 + 1];
                float rz = pos[j * 3 + 2] - pos[cc * 3 + 2];
                const float* lf = lframes + cc * 9;
                f4v r;
                r[0] = lf[0] * rx + lf[1] * ry + lf[2] * rz;
                r[1] = lf[3] * rx + lf[4] * ry + lf[5] * rz;
                r[2] = lf[6] * rx + lf[7] * ry + lf[8] * rz;
                r[3] = 0.0f;
                relc_lds[nb][g][t] = r;
            }
            v_lds[nb][tid >> 8][tid & 255] = v[(mbase + (tid >> 8)) * 256 + (tid & 255)];
        }
        __syncthreads();                                 // h ready (+ meta[nb])

        // ---- phase 2: [128x256] @ [256x256], B streamed from L2/L1
        f4v acc[4][4] = {};
        for (int k0 = 0; k0 < 256; k0 += 32) {
            s8v a[4], b[4];
            #pragma unroll
            for (int rt = 0; rt < 4; ++rt)
                a[rt] = *(const s8v*)&h_lds[(rbase + rt * 16 + l16) * 264 + k0 + quad * 8];
            #pragma unroll
            for (int ct = 0; ct < 4; ++ct)
                b[ct] = *(const s8v*)(W2T + (cb + ct * 16 + l16) * 256 + k0 + quad * 8);
            #pragma unroll
            for (int rt = 0; rt < 4; ++rt)
                #pragma unroll
                for (int ct = 0; ct < 4; ++ct)
                    acc[rt][ct] = __builtin_amdgcn_mfma_f32_16x16x32_bf16(a[rt], b[ct], acc[rt][ct], 0, 0, 0);
        }
        // ---- epilogue: masked max over this wave's center, + b2
        int mout = m0 + p * 2 + gsel;
        #pragma unroll
        for (int ct = 0; ct < 4; ++ct) {
            float mx = -__builtin_inff();
            #pragma unroll
            for (int rt = 0; rt < 4; ++rt)
                #pragma unroll
                for (int g = 0; g < 4; ++g) {
                    int row = rt * 16 + quad * 4 + g;
                    float val = acc[rt][ct][g];
                    if (row < cv_cur) mx = fmaxf(mx, val);
                }
            mx = fmaxf(mx, __shfl_xor(mx, 16, 64));
            mx = fmaxf(mx, __shfl_xor(mx, 32, 64));
            if (lane < 16)
                out0[mout * 256 + cb + ct * 16 + l16] = mx + b2[cb + ct * 16 + l16];
        }
        cv_cur = cv_next;
        __syncthreads();                                 // h consumed before next overwrite
    }
}

extern "C" void kernel_launch(void* const* d_in, const int* in_sizes, int n_in,
                              void* d_out, int out_size, void* d_ws, size_t ws_size,
                              hipStream_t stream) {
    const float* x       = (const float*)d_in[0];
    const float* pos     = (const float*)d_in[1];
    const int*   batch   = (const int*)d_in[2];
    const float* lframes = (const float*)d_in[3];
    const float* W1      = (const float*)d_in[4];
    const float* b1      = (const float*)d_in[5];
    const float* W2      = (const float*)d_in[6];
    const float* b2      = (const float*)d_in[7];

    float* out       = (float*)d_out;
    float* out_pos   = out + M_CTR * 256;
    float* out_batch = out_pos + M_CTR * 3;
    float* out_lf    = out_batch + M_CTR;

    char* ws = (char*)d_ws;
    u16*   u_ws = (u16*)(ws);                    // N*256 bf16   = 8 MB
    float* v_ws = (float*)(ws + 8388608);        // M*256 f32    = 4 MB
    u16*   W2T  = (u16*)(ws + 12713984);         // 256*256 bf16
    int*   nbr  = (int*)(ws + 12845056);         // M*64 int
    int*   cntp = (int*)(ws + 13893632);         // M int

    hipLaunchKernelGGL(work_kernel, dim3(M_CTR + 320), dim3(256), 0, stream,
                       pos, nbr, cntp, W1, W2, W2T, x, b1, u_ws, v_ws);
    hipLaunchKernelGGL(edge_kernel, dim3(512), dim3(512), 0, stream,
                       u_ws, v_ws, W2T, W1, b2, pos, lframes, batch, nbr, cntp,
                       out, out_pos, out_batch, out_lf);
}

// Round 10
// 186.821 us; speedup vs baseline: 1.3939x; 1.0837x over previous
//
#include <hip/hip_runtime.h>
#include <hip/hip_bf16.h>

#define N_PTS 16384
#define PER   2048
#define M_CTR 4096
#define KNB   64
#define C_IN  128
#define HID   256
#define C_OUT 256

typedef unsigned short u16;
typedef unsigned int u32;
typedef unsigned long long u64;
typedef __attribute__((ext_vector_type(8))) short s8v;    // 8 bf16 (4 VGPRs)
typedef __attribute__((ext_vector_type(4))) float f4v;
typedef __attribute__((ext_vector_type(4))) unsigned int u4v;

static __device__ __forceinline__ u16 f2bf(float f) {
    union { float f; unsigned int i; } v; v.f = f;
    unsigned int r = v.i + 0x7FFFu + ((v.i >> 16) & 1u);
    return (u16)(r >> 16);
}

// monotone float->uint: preserves total order for ALL floats incl. negatives.
// (r9 bug: gemm-trick d2 can be -epsilon for the center itself; raw bit
// packing sorted those LAST, dropping the nearest point from the top-64.)
static __device__ __forceinline__ u32 fkey(float f) {
    u32 b = __float_as_uint(f);
    return b ^ ((u32)((int)b >> 31) | 0x80000000u);
}

// ---------------------------------------------------------------- fused ballq (blocks 0..1023, wave-per-center) + gemm_xw (1024..1343)
// ballq: wave-autonomous, NO barriers / NO atomics. Compaction via ballot
// prefix with uniform register count. Candidates packed as u64 keys
// (fkey(d2)<<32)|idx -> one u64 compare implements (d2, idx) lexicographic
// rank = the reference's stable top_k. d2 arithmetic replicates the
// reference fp32 gemm-trick bit-for-bit (r2 notes).
__global__ __launch_bounds__(256) void work_kernel(
        const float* __restrict__ pos, int* __restrict__ nbr, int* __restrict__ cnt,
        const float* __restrict__ W1, const float* __restrict__ W2,
        u16* __restrict__ W2T,
        const float* __restrict__ x, const float* __restrict__ b1,
        u16* __restrict__ u_out, float* __restrict__ v_out) {
    __shared__ char arena[32768];
    int blk = blockIdx.x, tid = threadIdx.x;

    if (blk < 1024) {
        // ================= ballq: wave w -> center blk*4+w =================
        if (blk < 256) {                                  // W2T prep for edge
            int gid = blk * 256 + tid;
            int cc = gid >> 8, k = gid & 255;
            W2T[gid] = f2bf(W2[k * 256 + cc]);            // W2T[c][k]
        }
        int w = tid >> 6, ln = tid & 63;
        int m = blk * 4 + w;
        int c = m * 4;
        int base = (m >> 9) << 11;                        // cloud start
        u64* cand = (u64*)arena + w * 1024;               // 8 KB per wave

        float cx = pos[c * 3 + 0], cy = pos[c * 3 + 1], cz = pos[c * 3 + 2];
        float A = __fadd_rn(__fadd_rn(__fmul_rn(cx, cx), __fmul_rn(cy, cy)), __fmul_rn(cz, cz));
        float c2x = __fmul_rn(2.0f, cx);
        float c2y = __fmul_rn(2.0f, cy);
        float c2z = __fmul_rn(2.0f, cz);
        int count = 0;                                    // uniform across wave
        #pragma unroll 4
        for (int s = 0; s < 32; ++s) {
            int j = base + ln + (s << 6);
            float px = pos[j * 3 + 0], py = pos[j * 3 + 1], pz = pos[j * 3 + 2];
            float B = __fadd_rn(__fadd_rn(__fmul_rn(px, px), __fmul_rn(py, py)), __fmul_rn(pz, pz));
            float C = __fmaf_rn(c2z, pz, __fmaf_rn(c2y, py, __fmul_rn(c2x, px)));
            float d2 = __fsub_rn(__fadd_rn(A, B), C);
            bool hit = (d2 <= 0.0625f);
            u64 mk = __ballot(hit);
            if (hit) {
                int a = count + __popcll(mk & ((1ull << ln) - 1ull));
                if (a < 1024)
                    cand[a] = (((u64)fkey(d2)) << 32) | (u32)j;
            }
            count += __popcll(mk);                        // uniform
        }
        __builtin_amdgcn_wave_barrier();                  // order LDS writes vs reads
        int V = count < 1024 ? count : 1024;
        if (V <= KNB) {
            nbr[m * KNB + ln] = (ln < V) ? (int)(cand[ln] & 0xFFFFFFFFu) : c;
            if (ln == 0) cnt[m] = V;
        } else {
            if (ln == 0) cnt[m] = KNB;
            for (int e = ln; e < V; e += 64) {
                u64 ke = cand[e];
                int rank = 0;
                for (int q = 0; q < V; ++q)
                    rank += (cand[q] < ke);
                if (rank < KNB) nbr[m * KNB + rank] = (int)(ke & 0xFFFFFFFFu);
            }
        }
    } else {
        // ================= gemm_xw =================
        u16* x_lds = (u16*)arena;                         // [64*136]
        int blk2 = blk - 1024;
        int mode = blk2 >= 256 ? 1 : 0;
        int bb = mode ? blk2 - 256 : blk2;
        const float* W1x = W1 + (mode ? 128 * 256 : 0);
        {
            int r = tid >> 2, q = tid & 3;
            int xrow = bb * 64 + r;
            if (mode) xrow *= 4;
            const float* xp = x + xrow * C_IN + q * 32;
            u16* dst = x_lds + r * 136 + q * 32;
            for (int i = 0; i < 8; ++i) {
                f4v f = *(const f4v*)(xp + i * 4);
                dst[i * 4 + 0] = f2bf(f[0]);
                dst[i * 4 + 1] = f2bf(f[1]);
                dst[i * 4 + 2] = f2bf(f[2]);
                dst[i * 4 + 3] = f2bf(f[3]);
            }
        }
        __syncthreads();
        int lane = tid & 63, w = tid >> 6;
        int quad = lane >> 4, l16 = lane & 15;
        int cb = w * 64;
        f4v acc[4][4] = {};
        for (int k0 = 0; k0 < 128; k0 += 32) {
            s8v a[4], b[4];
            #pragma unroll
            for (int ct = 0; ct < 4; ++ct) {
                int col = cb + ct * 16 + l16;
                const float* wp = W1x + (k0 + quad * 8) * 256 + col;
                union { u4v v4; s8v s8; } pk;
                #pragma unroll
                for (int d = 0; d < 4; ++d) {
                    u16 lo = f2bf(wp[(2 * d) * 256]);
                    u16 hi = f2bf(wp[(2 * d + 1) * 256]);
                    pk.v4[d] = ((u32)hi << 16) | lo;
                }
                b[ct] = pk.s8;
            }
            #pragma unroll
            for (int rt = 0; rt < 4; ++rt)
                a[rt] = *(const s8v*)&x_lds[(rt * 16 + l16) * 136 + k0 + quad * 8];
            #pragma unroll
            for (int rt = 0; rt < 4; ++rt)
                #pragma unroll
                for (int ct = 0; ct < 4; ++ct)
                    acc[rt][ct] = __builtin_amdgcn_mfma_f32_16x16x32_bf16(a[rt], b[ct], acc[rt][ct], 0, 0, 0);
        }
        for (int rt = 0; rt < 4; ++rt)
            for (int ct = 0; ct < 4; ++ct)
                for (int g = 0; g < 4; ++g) {
                    int row = rt * 16 + quad * 4 + g;
                    int col = cb + ct * 16 + l16;
                    float val = acc[rt][ct][g];
                    int orow = bb * 64 + row;
                    if (mode == 0) u_out[orow * 256 + col] = f2bf(val);
                    else           v_out[orow * 256 + col] = val + b1[col];
                }
    }
}

// ---------------------------------------------------------------- fused edge conv
// 512 threads = 8 waves; M-tile 128; 4 pairs/block; grid 512. Single h buffer:
// 79 KB LDS -> 2 blocks/CU -> 4 waves/SIMD (occupancy via LDS, NOT via
// launch_bounds). (512,2) = 128-VGPR cap: the ONLY no-spill config measured
// (r4/r7: arg2=4 caps at 64 VGPR -> 300 MB scratch traffic).
__global__ __launch_bounds__(512, 2) void edge_kernel(
        const u16* __restrict__ u, const float* __restrict__ v,
        const u16* __restrict__ W2T, const float* __restrict__ W1,
        const float* __restrict__ b2, const float* __restrict__ pos,
        const float* __restrict__ lframes, const int* __restrict__ batch,
        const int* __restrict__ nbrg, const int* __restrict__ cnt,
        float* __restrict__ out0, float* __restrict__ out_pos,
        float* __restrict__ out_batch, float* __restrict__ out_lf) {
    __shared__ u16   h_lds[128 * 264];                   // 67584 B
    __shared__ float v_lds[2][2][256];                   // 4096 B
    __shared__ float w1c_lds[768];                       // 3072 B
    __shared__ f4v   relc_lds[2][2][64];                 // 4096 B
    __shared__ u16   nbr_lds[2][2][64];                  // 512 B

    int blk = blockIdx.x, tid = threadIdx.x;
    int m0 = ((blk & 7) << 9) | ((blk >> 3) << 3);       // 8 consecutive centers, cloud == XCD

    int lane = tid & 63, w = tid >> 6;
    int quad = lane >> 4, l16 = lane & 15;
    int cb = (w & 3) * 64;
    int rbase = (w >> 2) * 64;
    int gsel = w >> 2;

    // ---- prologue
    for (int i = tid; i < 768; i += 512) w1c_lds[i] = W1[65536 + i];
    if (tid < 128) {                                     // meta for pair 0
        int g = tid >> 6, t = tid & 63;
        int mm = m0 + g, cc = mm * 4;
        int j = nbrg[mm * KNB + t];
        nbr_lds[0][g][t] = (u16)j;
        float rx = pos[j * 3 + 0] - pos[cc * 3 + 0];
        float ry = pos[j * 3 + 1] - pos[cc * 3 + 1];
        float rz = pos[j * 3 + 2] - pos[cc * 3 + 2];
        const float* lf = lframes + cc * 9;
        f4v r;
        r[0] = lf[0] * rx + lf[1] * ry + lf[2] * rz;
        r[1] = lf[3] * rx + lf[4] * ry + lf[5] * rz;
        r[2] = lf[6] * rx + lf[7] * ry + lf[8] * rz;
        r[3] = 0.0f;
        relc_lds[0][g][t] = r;
    }
    v_lds[0][tid >> 8][tid & 255] = v[(m0 + (tid >> 8)) * 256 + (tid & 255)];
    if (tid >= 256 && tid < 384) {                       // aux outputs, all 8 centers
        int g = (tid - 256) >> 4, t = tid & 15;
        int mm = m0 + g, cc = mm * 4;
        if (t < 3)            out_pos[mm * 3 + t] = pos[cc * 3 + t];
        else if (t == 3)      out_batch[mm] = (float)batch[cc];
        else if (t < 13)      out_lf[mm * 9 + (t - 4)] = lframes[cc * 9 + (t - 4)];
    }

    int co = (tid & 31) * 8;
    int rs = tid >> 5;                                   // 0..15
    int cv_cur = cnt[m0 + gsel];
    __syncthreads();                                     // meta[0] + w1c ready

    int cv_next = 0;
    for (int p = 0; p < 4; ++p) {
        int pb = p & 1;
        // ---- phase 1: h[128][256] = relu(u[nbr] + v + relc @ W1c)
        #pragma unroll
        for (int g = 0; g < 2; ++g) {
            f4v vq0 = *(const f4v*)&v_lds[pb][g][co];
            f4v vq1 = *(const f4v*)&v_lds[pb][g][co + 4];
            f4v wa0 = *(const f4v*)&w1c_lds[co],       wa1 = *(const f4v*)&w1c_lds[co + 4];
            f4v wb0 = *(const f4v*)&w1c_lds[256 + co], wb1 = *(const f4v*)&w1c_lds[256 + co + 4];
            f4v wc0 = *(const f4v*)&w1c_lds[512 + co], wc1 = *(const f4v*)&w1c_lds[512 + co + 4];
            #pragma unroll
            for (int i2 = 0; i2 < 4; ++i2) {
                int rl = rs + i2 * 16;
                int row = g * 64 + rl;
                int j = (int)nbr_lds[pb][g][rl];
                u4v uu = *(const u4v*)(u + j * 256 + co);
                f4v r = relc_lds[pb][g][rl];
                float p8[8];
                #pragma unroll
                for (int e = 0; e < 8; ++e) {
                    u32 bits = (e & 1) ? (uu[e >> 1] & 0xFFFF0000u) : (uu[e >> 1] << 16);
                    float va = (e < 4) ? vq0[e] : vq1[e - 4];
                    float a0 = (e < 4) ? wa0[e] : wa1[e - 4];
                    float b0 = (e < 4) ? wb0[e] : wb1[e - 4];
                    float c0 = (e < 4) ? wc0[e] : wc1[e - 4];
                    float pre = fmaf(r[0], a0, fmaf(r[1], b0, fmaf(r[2], c0,
                                  va + __uint_as_float(bits))));
                    p8[e] = fmaxf(pre, 0.0f);
                }
                u4v pk;
                #pragma unroll
                for (int d = 0; d < 4; ++d)
                    pk[d] = __builtin_amdgcn_perm(__float_as_uint(p8[2 * d + 1]),
                                                  __float_as_uint(p8[2 * d]), 0x07060302u);
                *(u4v*)&h_lds[row * 264 + co] = pk;
            }
        }
        // ---- prefetch next pair's metadata into the other buffer
        if (p < 3) {
            int nb = pb ^ 1;
            int mbase = m0 + (p + 1) * 2;
            cv_next = cnt[mbase + gsel];
            if (tid < 128) {
                int g = tid >> 6, t = tid & 63;
                int mm = mbase + g, cc = mm * 4;
                int j = nbrg[mm * KNB + t];
                nbr_lds[nb][g][t] = (u16)j;
                float rx = pos[j * 3 + 0] - pos[cc * 3 + 0];
                float ry = pos[j * 3 + 1] - pos[cc * 3 + 1];
                float rz = pos[j * 3 + 2] - pos[cc * 3 + 2];
                const float* lf = lframes + cc * 9;
                f4v r;
                r[0] = lf[0] * rx + lf[1] * ry + lf[2] * rz;
                r[1] = lf[3] * rx + lf[4] * ry + lf[5] * rz;
                r[2] = lf[6] * rx + lf[7] * ry + lf[8] * rz;
                r[3] = 0.0f;
                relc_lds[nb][g][t] = r;
            }
            v_lds[nb][tid >> 8][tid & 255] = v[(mbase + (tid >> 8)) * 256 + (tid & 255)];
        }
        __syncthreads();                                 // h ready (+ meta[nb])

        // ---- phase 2: [128x256] @ [256x256], B streamed from L2/L1
        f4v acc[4][4] = {};
        for (int k0 = 0; k0 < 256; k0 += 32) {
            s8v a[4], b[4];
            #pragma unroll
            for (int rt = 0; rt < 4; ++rt)
                a[rt] = *(const s8v*)&h_lds[(rbase + rt * 16 + l16) * 264 + k0 + quad * 8];
            #pragma unroll
            for (int ct = 0; ct < 4; ++ct)
                b[ct] = *(const s8v*)(W2T + (cb + ct * 16 + l16) * 256 + k0 + quad * 8);
            #pragma unroll
            for (int rt = 0; rt < 4; ++rt)
                #pragma unroll
                for (int ct = 0; ct < 4; ++ct)
                    acc[rt][ct] = __builtin_amdgcn_mfma_f32_16x16x32_bf16(a[rt], b[ct], acc[rt][ct], 0, 0, 0);
        }
        // ---- epilogue: masked max over this wave's center, + b2
        int mout = m0 + p * 2 + gsel;
        #pragma unroll
        for (int ct = 0; ct < 4; ++ct) {
            float mx = -__builtin_inff();
            #pragma unroll
            for (int rt = 0; rt < 4; ++rt)
                #pragma unroll
                for (int g = 0; g < 4; ++g) {
                    int row = rt * 16 + quad * 4 + g;
                    float val = acc[rt][ct][g];
                    if (row < cv_cur) mx = fmaxf(mx, val);
                }
            mx = fmaxf(mx, __shfl_xor(mx, 16, 64));
            mx = fmaxf(mx, __shfl_xor(mx, 32, 64));
            if (lane < 16)
                out0[mout * 256 + cb + ct * 16 + l16] = mx + b2[cb + ct * 16 + l16];
        }
        cv_cur = cv_next;
        __syncthreads();                                 // h consumed before next overwrite
    }
}

extern "C" void kernel_launch(void* const* d_in, const int* in_sizes, int n_in,
                              void* d_out, int out_size, void* d_ws, size_t ws_size,
                              hipStream_t stream) {
    const float* x       = (const float*)d_in[0];
    const float* pos     = (const float*)d_in[1];
    const int*   batch   = (const int*)d_in[2];
    const float* lframes = (const float*)d_in[3];
    const float* W1      = (const float*)d_in[4];
    const float* b1      = (const float*)d_in[5];
    const float* W2      = (const float*)d_in[6];
    const float* b2      = (const float*)d_in[7];

    float* out       = (float*)d_out;
    float* out_pos   = out + M_CTR * 256;
    float* out_batch = out_pos + M_CTR * 3;
    float* out_lf    = out_batch + M_CTR;

    char* ws = (char*)d_ws;
    u16*   u_ws = (u16*)(ws);                    // N*256 bf16   = 8 MB
    float* v_ws = (float*)(ws + 8388608);        // M*256 f32    = 4 MB
    u16*   W2T  = (u16*)(ws + 12713984);         // 256*256 bf16
    int*   nbr  = (int*)(ws + 12845056);         // M*64 int
    int*   cntp = (int*)(ws + 13893632);         // M int

    hipLaunchKernelGGL(work_kernel, dim3(1024 + 320), dim3(256), 0, stream,
                       pos, nbr, cntp, W1, W2, W2T, x, b1, u_ws, v_ws);
    hipLaunchKernelGGL(edge_kernel, dim3(512), dim3(512), 0, stream,
                       u_ws, v_ws, W2T, W1, b2, pos, lframes, batch, nbr, cntp,
                       out, out_pos, out_batch, out_lf);
}

// Round 11
// 179.602 us; speedup vs baseline: 1.4500x; 1.0402x over previous
//
#include <hip/hip_runtime.h>
#include <hip/hip_bf16.h>

#define N_PTS 16384
#define PER   2048
#define M_CTR 4096
#define KNB   64
#define C_IN  128
#define HID   256
#define C_OUT 256

typedef unsigned short u16;
typedef unsigned int u32;
typedef unsigned long long u64;
typedef __attribute__((ext_vector_type(8))) short s8v;    // 8 bf16 (4 VGPRs)
typedef __attribute__((ext_vector_type(4))) float f4v;
typedef __attribute__((ext_vector_type(4))) unsigned int u4v;

static __device__ __forceinline__ u16 f2bf(float f) {
    union { float f; unsigned int i; } v; v.f = f;
    unsigned int r = v.i + 0x7FFFu + ((v.i >> 16) & 1u);
    return (u16)(r >> 16);
}

// monotone float->uint: preserves total order for ALL floats incl. negatives
// (r9 lesson: gemm-trick d2 can be -epsilon for the center itself).
static __device__ __forceinline__ u32 fkey(float f) {
    u32 b = __float_as_uint(f);
    return b ^ ((u32)((int)b >> 31) | 0x80000000u);
}

// ---------------------------------------------------------------- fused ballq (blocks 0..1023, wave-per-center) + gemm_xw (1024..1343)
// (unchanged from r10 — passed, absmax 0.0156)
__global__ __launch_bounds__(256) void work_kernel(
        const float* __restrict__ pos, int* __restrict__ nbr, int* __restrict__ cnt,
        const float* __restrict__ W1, const float* __restrict__ W2,
        u16* __restrict__ W2T,
        const float* __restrict__ x, const float* __restrict__ b1,
        u16* __restrict__ u_out, float* __restrict__ v_out) {
    __shared__ char arena[32768];
    int blk = blockIdx.x, tid = threadIdx.x;

    if (blk < 1024) {
        // ================= ballq: wave w -> center blk*4+w =================
        if (blk < 256) {                                  // W2T prep for edge
            int gid = blk * 256 + tid;
            int cc = gid >> 8, k = gid & 255;
            W2T[gid] = f2bf(W2[k * 256 + cc]);            // W2T[c][k]
        }
        int w = tid >> 6, ln = tid & 63;
        int m = blk * 4 + w;
        int c = m * 4;
        int base = (m >> 9) << 11;                        // cloud start
        u64* cand = (u64*)arena + w * 1024;               // 8 KB per wave

        float cx = pos[c * 3 + 0], cy = pos[c * 3 + 1], cz = pos[c * 3 + 2];
        float A = __fadd_rn(__fadd_rn(__fmul_rn(cx, cx), __fmul_rn(cy, cy)), __fmul_rn(cz, cz));
        float c2x = __fmul_rn(2.0f, cx);
        float c2y = __fmul_rn(2.0f, cy);
        float c2z = __fmul_rn(2.0f, cz);
        int count = 0;                                    // uniform across wave
        #pragma unroll 4
        for (int s = 0; s < 32; ++s) {
            int j = base + ln + (s << 6);
            float px = pos[j * 3 + 0], py = pos[j * 3 + 1], pz = pos[j * 3 + 2];
            float B = __fadd_rn(__fadd_rn(__fmul_rn(px, px), __fmul_rn(py, py)), __fmul_rn(pz, pz));
            float C = __fmaf_rn(c2z, pz, __fmaf_rn(c2y, py, __fmul_rn(c2x, px)));
            float d2 = __fsub_rn(__fadd_rn(A, B), C);
            bool hit = (d2 <= 0.0625f);
            u64 mk = __ballot(hit);
            if (hit) {
                int a = count + __popcll(mk & ((1ull << ln) - 1ull));
                if (a < 1024)
                    cand[a] = (((u64)fkey(d2)) << 32) | (u32)j;
            }
            count += __popcll(mk);                        // uniform
        }
        __builtin_amdgcn_wave_barrier();                  // order LDS writes vs reads
        int V = count < 1024 ? count : 1024;
        if (V <= KNB) {
            nbr[m * KNB + ln] = (ln < V) ? (int)(cand[ln] & 0xFFFFFFFFu) : c;
            if (ln == 0) cnt[m] = V;
        } else {
            if (ln == 0) cnt[m] = KNB;
            for (int e = ln; e < V; e += 64) {
                u64 ke = cand[e];
                int rank = 0;
                for (int q = 0; q < V; ++q)
                    rank += (cand[q] < ke);
                if (rank < KNB) nbr[m * KNB + rank] = (int)(ke & 0xFFFFFFFFu);
            }
        }
    } else {
        // ================= gemm_xw =================
        u16* x_lds = (u16*)arena;                         // [64*136]
        int blk2 = blk - 1024;
        int mode = blk2 >= 256 ? 1 : 0;
        int bb = mode ? blk2 - 256 : blk2;
        const float* W1x = W1 + (mode ? 128 * 256 : 0);
        {
            int r = tid >> 2, q = tid & 3;
            int xrow = bb * 64 + r;
            if (mode) xrow *= 4;
            const float* xp = x + xrow * C_IN + q * 32;
            u16* dst = x_lds + r * 136 + q * 32;
            for (int i = 0; i < 8; ++i) {
                f4v f = *(const f4v*)(xp + i * 4);
                dst[i * 4 + 0] = f2bf(f[0]);
                dst[i * 4 + 1] = f2bf(f[1]);
                dst[i * 4 + 2] = f2bf(f[2]);
                dst[i * 4 + 3] = f2bf(f[3]);
            }
        }
        __syncthreads();
        int lane = tid & 63, w = tid >> 6;
        int quad = lane >> 4, l16 = lane & 15;
        int cb = w * 64;
        f4v acc[4][4] = {};
        for (int k0 = 0; k0 < 128; k0 += 32) {
            s8v a[4], b[4];
            #pragma unroll
            for (int ct = 0; ct < 4; ++ct) {
                int col = cb + ct * 16 + l16;
                const float* wp = W1x + (k0 + quad * 8) * 256 + col;
                union { u4v v4; s8v s8; } pk;
                #pragma unroll
                for (int d = 0; d < 4; ++d) {
                    u16 lo = f2bf(wp[(2 * d) * 256]);
                    u16 hi = f2bf(wp[(2 * d + 1) * 256]);
                    pk.v4[d] = ((u32)hi << 16) | lo;
                }
                b[ct] = pk.s8;
            }
            #pragma unroll
            for (int rt = 0; rt < 4; ++rt)
                a[rt] = *(const s8v*)&x_lds[(rt * 16 + l16) * 136 + k0 + quad * 8];
            #pragma unroll
            for (int rt = 0; rt < 4; ++rt)
                #pragma unroll
                for (int ct = 0; ct < 4; ++ct)
                    acc[rt][ct] = __builtin_amdgcn_mfma_f32_16x16x32_bf16(a[rt], b[ct], acc[rt][ct], 0, 0, 0);
        }
        for (int rt = 0; rt < 4; ++rt)
            for (int ct = 0; ct < 4; ++ct)
                for (int g = 0; g < 4; ++g) {
                    int row = rt * 16 + quad * 4 + g;
                    int col = cb + ct * 16 + l16;
                    float val = acc[rt][ct][g];
                    int orow = bb * 64 + row;
                    if (mode == 0) u_out[orow * 256 + col] = f2bf(val);
                    else           v_out[orow * 256 + col] = val + b1[col];
                }
    }
}

// ---------------------------------------------------------------- fused edge conv
// 1024 threads = 16 waves; M-tile 128 (2 centers); 8 pairs/block; grid 256.
// Wave w: rows (w>>3)*64 (one center), cols (w&7)*32 -> acc = 32 AGPRs/wave.
// r10 lesson: acc 64 + VGPR 128 = ~192 unified regs -> only 8 waves/CU fit.
// Halving acc doubles resident waves: 16 waves/CU = 4 waves/SIMD at the same
// 79 KB LDS. (1024,1) keeps the measured 128-reg no-spill cap.
__global__ __launch_bounds__(1024, 1) void edge_kernel(
        const u16* __restrict__ u, const float* __restrict__ v,
        const u16* __restrict__ W2T, const float* __restrict__ W1,
        const float* __restrict__ b2, const float* __restrict__ pos,
        const float* __restrict__ lframes, const int* __restrict__ batch,
        const int* __restrict__ nbrg, const int* __restrict__ cnt,
        float* __restrict__ out0, float* __restrict__ out_pos,
        float* __restrict__ out_batch, float* __restrict__ out_lf) {
    __shared__ u16   h_lds[128 * 264];                   // 67584 B
    __shared__ float v_lds[2][2][256];                   // 4096 B
    __shared__ float w1c_lds[768];                       // 3072 B
    __shared__ f4v   relc_lds[2][2][64];                 // 4096 B
    __shared__ u16   nbr_lds[2][2][64];                  // 512 B

    int blk = blockIdx.x, tid = threadIdx.x;
    int m0 = ((blk & 7) << 9) | ((blk >> 3) << 4);       // 16 consecutive centers, cloud == XCD

    int lane = tid & 63, w = tid >> 6;                   // w: 0..15
    int quad = lane >> 4, l16 = lane & 15;
    int cb = (w & 7) * 32;                               // 32-col slice
    int gsel = w >> 3;                                   // wave's center within pair
    int rbase = gsel * 64;

    // ---- prologue
    if (tid < 768) w1c_lds[tid] = W1[65536 + tid];
    if (tid < 128) {                                     // meta for pair 0
        int g = tid >> 6, t = tid & 63;
        int mm = m0 + g, cc = mm * 4;
        int j = nbrg[mm * KNB + t];
        nbr_lds[0][g][t] = (u16)j;
        float rx = pos[j * 3 + 0] - pos[cc * 3 + 0];
        float ry = pos[j * 3 + 1] - pos[cc * 3 + 1];
        float rz = pos[j * 3 + 2] - pos[cc * 3 + 2];
        const float* lf = lframes + cc * 9;
        f4v r;
        r[0] = lf[0] * rx + lf[1] * ry + lf[2] * rz;
        r[1] = lf[3] * rx + lf[4] * ry + lf[5] * rz;
        r[2] = lf[6] * rx + lf[7] * ry + lf[8] * rz;
        r[3] = 0.0f;
        relc_lds[0][g][t] = r;
    }
    if (tid < 512)
        v_lds[0][tid >> 8][tid & 255] = v[(m0 + (tid >> 8)) * 256 + (tid & 255)];
    if (tid >= 512 && tid < 768) {                       // aux outputs, all 16 centers
        int t16 = tid - 512;
        int g = t16 >> 4, t = t16 & 15;
        int mm = m0 + g, cc = mm * 4;
        if (t < 3)            out_pos[mm * 3 + t] = pos[cc * 3 + t];
        else if (t == 3)      out_batch[mm] = (float)batch[cc];
        else if (t < 13)      out_lf[mm * 9 + (t - 4)] = lframes[cc * 9 + (t - 4)];
    }

    int co = (tid & 31) * 8;                             // 8-col slice
    int rs = tid >> 5;                                   // 0..31
    int cv_cur = cnt[m0 + gsel];
    __syncthreads();                                     // meta[0] + w1c ready

    int cv_next = 0;
    for (int p = 0; p < 8; ++p) {
        int pb = p & 1;
        // ---- phase 1: h[128][256] = relu(u[nbr] + v + relc @ W1c); 4 rows/thread
        #pragma unroll
        for (int g = 0; g < 2; ++g) {
            f4v vq0 = *(const f4v*)&v_lds[pb][g][co];
            f4v vq1 = *(const f4v*)&v_lds[pb][g][co + 4];
            f4v wa0 = *(const f4v*)&w1c_lds[co],       wa1 = *(const f4v*)&w1c_lds[co + 4];
            f4v wb0 = *(const f4v*)&w1c_lds[256 + co], wb1 = *(const f4v*)&w1c_lds[256 + co + 4];
            f4v wc0 = *(const f4v*)&w1c_lds[512 + co], wc1 = *(const f4v*)&w1c_lds[512 + co + 4];
            #pragma unroll
            for (int i2 = 0; i2 < 2; ++i2) {
                int rl = rs + i2 * 32;                   // row within center
                int row = g * 64 + rl;
                int j = (int)nbr_lds[pb][g][rl];
                u4v uu = *(const u4v*)(u + j * 256 + co);
                f4v r = relc_lds[pb][g][rl];
                float p8[8];
                #pragma unroll
                for (int e = 0; e < 8; ++e) {
                    u32 bits = (e & 1) ? (uu[e >> 1] & 0xFFFF0000u) : (uu[e >> 1] << 16);
                    float va = (e < 4) ? vq0[e] : vq1[e - 4];
                    float a0 = (e < 4) ? wa0[e] : wa1[e - 4];
                    float b0 = (e < 4) ? wb0[e] : wb1[e - 4];
                    float c0 = (e < 4) ? wc0[e] : wc1[e - 4];
                    float pre = fmaf(r[0], a0, fmaf(r[1], b0, fmaf(r[2], c0,
                                  va + __uint_as_float(bits))));
                    p8[e] = fmaxf(pre, 0.0f);
                }
                u4v pk;
                #pragma unroll
                for (int d = 0; d < 4; ++d)
                    pk[d] = __builtin_amdgcn_perm(__float_as_uint(p8[2 * d + 1]),
                                                  __float_as_uint(p8[2 * d]), 0x07060302u);
                *(u4v*)&h_lds[row * 264 + co] = pk;
            }
        }
        // ---- prefetch next pair's metadata into the other buffer
        if (p < 7) {
            int nb = pb ^ 1;
            int mbase = m0 + (p + 1) * 2;
            cv_next = cnt[mbase + gsel];
            if (tid < 128) {
                int g = tid >> 6, t = tid & 63;
                int mm = mbase + g, cc = mm * 4;
                int j = nbrg[mm * KNB + t];
                nbr_lds[nb][g][t] = (u16)j;
                float rx = pos[j * 3 + 0] - pos[cc * 3 + 0];
                float ry = pos[j * 3 + 1] - pos[cc * 3 + 1];
                float rz = pos[j * 3 + 2] - pos[cc * 3 + 2];
                const float* lf = lframes + cc * 9;
                f4v r;
                r[0] = lf[0] * rx + lf[1] * ry + lf[2] * rz;
                r[1] = lf[3] * rx + lf[4] * ry + lf[5] * rz;
                r[2] = lf[6] * rx + lf[7] * ry + lf[8] * rz;
                r[3] = 0.0f;
                relc_lds[nb][g][t] = r;
            }
            if (tid < 512)
                v_lds[nb][tid >> 8][tid & 255] = v[(mbase + (tid >> 8)) * 256 + (tid & 255)];
        }
        __syncthreads();                                 // h ready (+ meta[nb])

        // ---- phase 2: [128x256] @ [256x256]; wave: 64 rows x 32 cols
        f4v acc[4][2] = {};
        for (int k0 = 0; k0 < 256; k0 += 32) {
            s8v a[4], b[2];
            #pragma unroll
            for (int rt = 0; rt < 4; ++rt)
                a[rt] = *(const s8v*)&h_lds[(rbase + rt * 16 + l16) * 264 + k0 + quad * 8];
            #pragma unroll
            for (int ct = 0; ct < 2; ++ct)
                b[ct] = *(const s8v*)(W2T + (cb + ct * 16 + l16) * 256 + k0 + quad * 8);
            #pragma unroll
            for (int rt = 0; rt < 4; ++rt)
                #pragma unroll
                for (int ct = 0; ct < 2; ++ct)
                    acc[rt][ct] = __builtin_amdgcn_mfma_f32_16x16x32_bf16(a[rt], b[ct], acc[rt][ct], 0, 0, 0);
        }
        // ---- epilogue: masked max over this wave's center, + b2
        int mout = m0 + p * 2 + gsel;
        #pragma unroll
        for (int ct = 0; ct < 2; ++ct) {
            float mx = -__builtin_inff();
            #pragma unroll
            for (int rt = 0; rt < 4; ++rt)
                #pragma unroll
                for (int g = 0; g < 4; ++g) {
                    int row = rt * 16 + quad * 4 + g;
                    float val = acc[rt][ct][g];
                    if (row < cv_cur) mx = fmaxf(mx, val);
                }
            mx = fmaxf(mx, __shfl_xor(mx, 16, 64));
            mx = fmaxf(mx, __shfl_xor(mx, 32, 64));
            if (lane < 16)
                out0[mout * 256 + cb + ct * 16 + l16] = mx + b2[cb + ct * 16 + l16];
        }
        cv_cur = cv_next;
        __syncthreads();                                 // h consumed before next overwrite
    }
}

extern "C" void kernel_launch(void* const* d_in, const int* in_sizes, int n_in,
                              void* d_out, int out_size, void* d_ws, size_t ws_size,
                              hipStream_t stream) {
    const float* x       = (const float*)d_in[0];
    const float* pos     = (const float*)d_in[1];
    const int*   batch   = (const int*)d_in[2];
    const float* lframes = (const float*)d_in[3];
    const float* W1      = (const float*)d_in[4];
    const float* b1      = (const float*)d_in[5];
    const float* W2      = (const float*)d_in[6];
    const float* b2      = (const float*)d_in[7];

    float* out       = (float*)d_out;
    float* out_pos   = out + M_CTR * 256;
    float* out_batch = out_pos + M_CTR * 3;
    float* out_lf    = out_batch + M_CTR;

    char* ws = (char*)d_ws;
    u16*   u_ws = (u16*)(ws);                    // N*256 bf16   = 8 MB
    float* v_ws = (float*)(ws + 8388608);        // M*256 f32    = 4 MB
    u16*   W2T  = (u16*)(ws + 12713984);         // 256*256 bf16
    int*   nbr  = (int*)(ws + 12845056);         // M*64 int
    int*   cntp = (int*)(ws + 13893632);         // M int

    hipLaunchKernelGGL(work_kernel, dim3(1024 + 320), dim3(256), 0, stream,
                       pos, nbr, cntp, W1, W2, W2T, x, b1, u_ws, v_ws);
    hipLaunchKernelGGL(edge_kernel, dim3(256), dim3(1024), 0, stream,
                       u_ws, v_ws, W2T, W1, b2, pos, lframes, batch, nbr, cntp,
                       out, out_pos, out_batch, out_lf);
}